// Round 1
// baseline (1272.012 us; speedup 1.0000x reference)
//
#include <hip/hip_runtime.h>
#include <stdint.h>
#include <math.h>

#define B_   16
#define T_   50
#define C_   200
#define N_   10000      // T_*C_
#define NT_  160000     // B_*N_
#define H_   8
#define E_   5120000
#define EPS_ 1e-5f

// ---------------- Threefry-2x32 (JAX) ----------------
struct TF2C { unsigned a, b; };
constexpr unsigned rotl32c(unsigned v, int r){ return (v << r) | (v >> (32 - r)); }
constexpr TF2C tf_const(unsigned k0, unsigned k1, unsigned x0, unsigned x1){
  unsigned ks2 = k0 ^ k1 ^ 0x1BD11BDAu;
  unsigned ks[3] = {k0, k1, ks2};
  x0 += k0; x1 += k1;
  const int RA[4] = {13, 15, 26, 6};
  const int RB[4] = {17, 29, 16, 24};
  for (int g = 0; g < 5; ++g){
    for (int r = 0; r < 4; ++r){
      int rr = (g & 1) ? RB[r] : RA[r];
      x0 += x1; x1 = rotl32c(x1, rr); x1 ^= x0;
    }
    x0 += ks[(g + 1) % 3];
    x1 += ks[(g + 2) % 3] + (unsigned)(g + 1);
  }
  return TF2C{x0, x1};
}
// rk = key(42) = (0,42); fold_in(rk, d) = threefry2x32(rk, (0, d))
constexpr TF2C KG = tf_const(0u, 42u, 0u, 0u);  // gumbel key
constexpr TF2C KN = tf_const(0u, 42u, 0u, 1u);  // noise key

__device__ __forceinline__ unsigned rotl32(unsigned v, int r){ return (v << r) | (v >> (32 - r)); }
__device__ __forceinline__ void tf2(unsigned k0, unsigned k1, unsigned x0, unsigned x1,
                                    unsigned &o0, unsigned &o1){
  unsigned ks2 = k0 ^ k1 ^ 0x1BD11BDAu;
  x0 += k0; x1 += k1;
#define TFR_(R) { x0 += x1; x1 = rotl32(x1, R); x1 ^= x0; }
  TFR_(13) TFR_(15) TFR_(26) TFR_(6)  x0 += k1;  x1 += ks2 + 1u;
  TFR_(17) TFR_(29) TFR_(16) TFR_(24) x0 += ks2; x1 += k0 + 2u;
  TFR_(13) TFR_(15) TFR_(26) TFR_(6)  x0 += k0;  x1 += k1 + 3u;
  TFR_(17) TFR_(29) TFR_(16) TFR_(24) x0 += k1;  x1 += ks2 + 4u;
  TFR_(13) TFR_(15) TFR_(26) TFR_(6)  x0 += ks2; x1 += k0 + 5u;
#undef TFR_
  o0 = x0; o1 = x1;
}
// partitionable random_bits: counter (hi=0, lo=m), output = b1 ^ b2
__device__ __forceinline__ unsigned rbits(unsigned ka, unsigned kb, unsigned m){
  unsigned a, b; tf2(ka, kb, 0u, m, a, b); return a ^ b;
}

// XLA ErfInv (f32, Giles)
__device__ __forceinline__ float erfinv_xla(float x){
  float w = -log1pf(-x * x);
  float p;
  if (w < 5.0f){
    w = w - 2.5f;
    p = 2.81022636e-08f;
    p = fmaf(p, w, 3.43273939e-07f);
    p = fmaf(p, w, -3.5233877e-06f);
    p = fmaf(p, w, -4.39150654e-06f);
    p = fmaf(p, w, 0.00021858087f);
    p = fmaf(p, w, -0.00125372503f);
    p = fmaf(p, w, -0.00417768164f);
    p = fmaf(p, w, 0.246640727f);
    p = fmaf(p, w, 1.50140941f);
  } else {
    w = sqrtf(w) - 3.0f;
    p = -0.000200214257f;
    p = fmaf(p, w, 0.000100950558f);
    p = fmaf(p, w, 0.00134934322f);
    p = fmaf(p, w, -0.00367342844f);
    p = fmaf(p, w, 0.00573950773f);
    p = fmaf(p, w, -0.0076224613f);
    p = fmaf(p, w, 0.00943887047f);
    p = fmaf(p, w, 1.00167406f);
    p = fmaf(p, w, 2.83297682f);
  }
  return p * x;
}

// ---------------- CSR build ----------------
__global__ void k_zero(int* __restrict__ cnts, float* __restrict__ stats){
  int n = blockIdx.x * 256 + threadIdx.x;
  if (n < NT_) cnts[n] = 0;
  if (n < 8) stats[n] = 0.f;
}

__global__ void k_count(const int* __restrict__ dst, int* __restrict__ cnts){
  int e = blockIdx.x * 256 + threadIdx.x;
  if (e < E_) atomicAdd(&cnts[dst[e]], 1);
}

#define SCB_ 1024
#define NSB_ 157    // ceil(160000/1024)

__global__ void k_scan1(const int* __restrict__ cnts, int* __restrict__ bsum){
  __shared__ int sred[4];
  int blk = blockIdx.x, tid = threadIdx.x;
  int base = blk * SCB_ + tid * 4;
  int s = 0;
#pragma unroll
  for (int k = 0; k < 4; ++k){
    int idx = base + k;
    s += (idx < NT_) ? cnts[idx] : 0;
  }
#pragma unroll
  for (int sh = 32; sh >= 1; sh >>= 1) s += __shfl_xor(s, sh, 64);
  int w = tid >> 6, l = tid & 63;
  if (l == 0) sred[w] = s;
  __syncthreads();
  if (tid == 0) bsum[blk] = sred[0] + sred[1] + sred[2] + sred[3];
}

__global__ void k_scan2(int* __restrict__ bsum){
  int acc = 0;
  for (int i = 0; i < NSB_; ++i){ int v = bsum[i]; bsum[i] = acc; acc += v; }
}

__global__ void k_scan3(int* __restrict__ cnts /* in: counts, out: cursor */,
                        const int* __restrict__ bsum,
                        int* __restrict__ offs){
  __shared__ int tsum[256];
  int blk = blockIdx.x, tid = threadIdx.x;
  int base = blk * SCB_ + tid * 4;
  int c0 = 0, c1 = 0, c2 = 0, c3 = 0;
  if (base + 0 < NT_) c0 = cnts[base + 0];
  if (base + 1 < NT_) c1 = cnts[base + 1];
  if (base + 2 < NT_) c2 = cnts[base + 2];
  if (base + 3 < NT_) c3 = cnts[base + 3];
  int tot = c0 + c1 + c2 + c3;
  tsum[tid] = tot;
  __syncthreads();
  for (int d = 1; d < 256; d <<= 1){
    int vv = (tid >= d) ? tsum[tid - d] : 0;
    __syncthreads();
    tsum[tid] += vv;
    __syncthreads();
  }
  int run = bsum[blk] + tsum[tid] - tot;
  if (base + 0 < NT_){ offs[base + 0] = run; cnts[base + 0] = run; run += c0; }
  if (base + 1 < NT_){ offs[base + 1] = run; cnts[base + 1] = run; run += c1; }
  if (base + 2 < NT_){ offs[base + 2] = run; cnts[base + 2] = run; run += c2; }
  if (base + 3 < NT_){ offs[base + 3] = run; cnts[base + 3] = run; run += c3; }
  if (blk == 0 && tid == 0) offs[NT_] = E_;
}

__global__ void k_scatter(const int* __restrict__ src, const int* __restrict__ dst,
                          int* __restrict__ cursor, int* __restrict__ srcs){
  int e = blockIdx.x * 256 + threadIdx.x;
  if (e < E_){
    int d = dst[e];
    int pos = atomicAdd(&cursor[d], 1);
    srcs[pos] = src[e];
  }
}

// ---------------- permutation layer ----------------
#define CHUNK_ 40
#define CHP_   41

__global__ __launch_bounds__(256, 4)
void k_perm(const float* __restrict__ W, const float* __restrict__ x,
            float* __restrict__ y, float* __restrict__ stats){
  __shared__ float xsh[C_];
  __shared__ float zch[C_ * CHP_];
  __shared__ float ypart[4 * C_];
  __shared__ float sred[8];

  const int bid = blockIdx.x;            // t*B_ + b
  const int t = bid / B_;
  const int b = bid - t * B_;
  const unsigned base_m = (unsigned)bid * (unsigned)(C_ * C_);
  const int xoff = (b * T_ + t) * C_;
  const int tid = threadIdx.x;
  const int w = tid >> 6, l = tid & 63;

  if (tid < C_) xsh[tid] = x[xoff + tid];

  float yacc0 = 0.f, yacc1 = 0.f, yacc2 = 0.f, yacc3 = 0.f;

  for (int j0 = 0; j0 < C_; j0 += CHUNK_){
    __syncthreads();
    // stage z = W + gumbel, coalesced over rows
    for (int e = tid; e < C_ * CHUNK_; e += 256){
      int i = e / CHUNK_;
      int jj = e - i * CHUNK_;
      unsigned m = base_m + (unsigned)(i * C_ + j0 + jj);
      unsigned bits = rbits(KG.a, KG.b, m);
      float f = __uint_as_float((bits >> 9) | 0x3f800000u) - 1.0f;   // [0,1)
      float u = fmaxf(1e-10f, f + 1e-10f);                           // uniform(1e-10, 1)
      float g = -logf(-logf(u));
      zch[i * CHP_ + jj] = W[(size_t)base_m + (size_t)(i * C_ + j0 + jj)] + g;
    }
    __syncthreads();
    // column softmax (axis = i) + accumulate y
    for (int jj = w; jj < CHUNK_; jj += 4){
      float z0 = zch[l * CHP_ + jj];
      float z1 = zch[(l + 64) * CHP_ + jj];
      float z2 = zch[(l + 128) * CHP_ + jj];
      float z3 = (l < 8) ? zch[(l + 192) * CHP_ + jj] : -INFINITY;
      float mx = fmaxf(fmaxf(z0, z1), fmaxf(z2, z3));
#pragma unroll
      for (int s = 32; s >= 1; s >>= 1) mx = fmaxf(mx, __shfl_xor(mx, s, 64));
      float e0 = expf(z0 - mx), e1 = expf(z1 - mx), e2 = expf(z2 - mx);
      float e3 = (l < 8) ? expf(z3 - mx) : 0.0f;
      float se = e0 + e1 + e2 + e3;
#pragma unroll
      for (int s = 32; s >= 1; s >>= 1) se += __shfl_xor(se, s, 64);
      float wj = xsh[j0 + jj] / se;
      yacc0 = fmaf(e0, wj, yacc0);
      yacc1 = fmaf(e1, wj, yacc1);
      yacc2 = fmaf(e2, wj, yacc2);
      yacc3 = fmaf(e3, wj, yacc3);
    }
  }
  __syncthreads();
  ypart[w * C_ + l] = yacc0;
  ypart[w * C_ + l + 64] = yacc1;
  ypart[w * C_ + l + 128] = yacc2;
  if (l < 8) ypart[w * C_ + l + 192] = yacc3;
  __syncthreads();

  float nzs = 0.f, nzc = 0.f;
  if (tid < C_){
    float v = ypart[tid] + ypart[C_ + tid] + ypart[2 * C_ + tid] + ypart[3 * C_ + tid];
    y[xoff + tid] = v;
    if (v != 0.0f){ nzs = v; nzc = 1.0f; }
  }
#pragma unroll
  for (int s = 32; s >= 1; s >>= 1){
    nzs += __shfl_xor(nzs, s, 64);
    nzc += __shfl_xor(nzc, s, 64);
  }
  if (l == 0){ sred[w] = nzs; sred[4 + w] = nzc; }
  __syncthreads();
  if (tid == 0){
    atomicAdd(&stats[0], sred[0] + sred[1] + sred[2] + sred[3]);
    atomicAdd(&stats[1], sred[4] + sred[5] + sred[6] + sred[7]);
  }
}

// ---------------- noise stats ----------------
__global__ void k_mean(float* __restrict__ stats){ stats[2] = stats[0] / stats[1]; }

__global__ void k_ssq(const float* __restrict__ y, float* __restrict__ stats){
  __shared__ float sred[4];
  int n = blockIdx.x * 256 + threadIdx.x;
  float mean = stats[2];
  float a = 0.f;
  float v = y[n];
  if (v != 0.f){ float d = v - mean; a = d * d; }
#pragma unroll
  for (int s = 32; s >= 1; s >>= 1) a += __shfl_xor(a, s, 64);
  int w = threadIdx.x >> 6, l = threadIdx.x & 63;
  if (l == 0) sred[w] = a;
  __syncthreads();
  if (threadIdx.x == 0) atomicAdd(&stats[3], sred[0] + sred[1] + sred[2] + sred[3]);
}

__global__ void k_noise(const float* __restrict__ y, const float* __restrict__ stats,
                        float* __restrict__ x0){
  int n = blockIdx.x * 256 + threadIdx.x;
  float v = y[n];
  if (v != 0.0f){ x0[n] = v; return; }
  float std_ = sqrtf(stats[3] / (stats[1] - 1.0f));
  float scale = std_ / 100.0f;
  unsigned bits = rbits(KN.a, KN.b, (unsigned)n);
  float f = __uint_as_float((bits >> 9) | 0x3f800000u) - 1.0f;
  float u = f * 2.0f + (-0.99999994f);       // uniform(nextafter(-1,0), 1)
  u = fmaxf(-0.99999994f, u);
  float nrm = 1.41421356237f * erfinv_xla(u);
  x0[n] = scale * nrm;
}

// ---------------- fused GAT pass (+BN+SiLU+residual) ----------------
__global__ __launch_bounds__(256)
void k_gat(const float* __restrict__ xin, const float* __restrict__ xres,
           const int* __restrict__ offs, const int* __restrict__ srcs,
           const float* __restrict__ gw, const float* __restrict__ asrc,
           const float* __restrict__ adst, const float* __restrict__ gbias,
           const float* __restrict__ bng, const float* __restrict__ bnb,
           const float* __restrict__ bnm, const float* __restrict__ bnv,
           float* __restrict__ xout){
  int n = blockIdx.x * 256 + threadIdx.x;
  if (n >= NT_) return;
  float wv[H_], cs[H_], cd[H_];
#pragma unroll
  for (int h = 0; h < H_; ++h){
    wv[h] = gw[h];
    cs[h] = wv[h] * asrc[h];
    cd[h] = wv[h] * adst[h];
  }
  float xn = xin[n];
  int e0 = offs[n], e1 = offs[n + 1];

  float mh[H_];
#pragma unroll
  for (int h = 0; h < H_; ++h){
    float v = cs[h] * xn + cd[h] * xn;        // self loop
    mh[h] = (v > 0.f) ? v : 0.2f * v;
  }
  for (int e = e0; e < e1; ++e){
    float xs = xin[srcs[e]];
#pragma unroll
    for (int h = 0; h < H_; ++h){
      float v = cs[h] * xs + cd[h] * xn;
      v = (v > 0.f) ? v : 0.2f * v;
      mh[h] = fmaxf(mh[h], v);
    }
  }
  float den[H_], num[H_];
#pragma unroll
  for (int h = 0; h < H_; ++h){
    float v = cs[h] * xn + cd[h] * xn;
    v = (v > 0.f) ? v : 0.2f * v;
    float ee = expf(v - mh[h]);
    den[h] = ee; num[h] = ee * xn;
  }
  for (int e = e0; e < e1; ++e){
    float xs = xin[srcs[e]];
#pragma unroll
    for (int h = 0; h < H_; ++h){
      float v = cs[h] * xs + cd[h] * xn;
      v = (v > 0.f) ? v : 0.2f * v;
      float ee = expf(v - mh[h]);
      den[h] += ee; num[h] += ee * xs;
    }
  }
  float o = 0.f;
#pragma unroll
  for (int h = 0; h < H_; ++h) o += wv[h] * num[h] / den[h];
  o = o * 0.125f + gbias[0];
  o = (o - bnm[0]) / sqrtf(bnv[0] + EPS_) * bng[0] + bnb[0];
  o = o / (1.0f + expf(-o));                  // silu
  xout[n] = o + xres[n];                      // persist^i = 1
}

// ---------------- final pool + linear + relu ----------------
__global__ void k_pool(const float* __restrict__ xf, const float* __restrict__ dv,
                       const float* __restrict__ lw, const float* __restrict__ lb,
                       float* __restrict__ out){
  __shared__ float sred[4];
  int b = blockIdx.x, tid = threadIdx.x;
  float m = -INFINITY;
  for (int li = tid; li < N_; li += 256){
    float v = xf[b * N_ + li] * dv[li];
    m = fmaxf(m, v);
  }
#pragma unroll
  for (int s = 32; s >= 1; s >>= 1) m = fmaxf(m, __shfl_xor(m, s, 64));
  int w = tid >> 6, l = tid & 63;
  if (l == 0) sred[w] = m;
  __syncthreads();
  if (tid == 0){
    float p = fmaxf(fmaxf(sred[0], sred[1]), fmaxf(sred[2], sred[3]));
    float o = p * lw[0] + lb[0];
    out[b] = (o > 0.f) ? o : 0.f;
  }
}

// ---------------- launch ----------------
extern "C" void kernel_launch(void* const* d_in, const int* in_sizes, int n_in,
                              void* d_out, int out_size, void* d_ws, size_t ws_size,
                              hipStream_t stream){
  const float* x     = (const float*)d_in[0];
  const int*   ei    = (const int*)d_in[1];
  const float* W     = (const float*)d_in[3];
  const float* dv    = (const float*)d_in[4];
  const float* gw    = (const float*)d_in[5];
  const float* asrc  = (const float*)d_in[6];
  const float* adst  = (const float*)d_in[7];
  const float* gbias = (const float*)d_in[8];
  const float* bng   = (const float*)d_in[9];
  const float* bnb   = (const float*)d_in[10];
  const float* bnm   = (const float*)d_in[11];
  const float* bnv   = (const float*)d_in[12];
  const float* lw    = (const float*)d_in[13];
  const float* lb    = (const float*)d_in[14];
  float* out = (float*)d_out;

  char* ws = (char*)d_ws;
  int*   offs  = (int*)(ws + 0);           // NT_+1 ints
  int*   cnts  = (int*)(ws + 640256);      // NT_ ints (counts, then cursor)
  int*   srcs  = (int*)(ws + 1280512);     // E_ ints
  float* y     = (float*)(ws + 21760512);  // NT_ f32 (x_res)
  float* x0    = (float*)(ws + 22400768);  // NT_ f32
  float* x1    = (float*)(ws + 23041024);  // NT_ f32
  int*   bsum  = (int*)(ws + 23681280);    // NSB_ ints
  float* stats = (float*)(ws + 23682304);  // 8 f32
  if (ws_size < (size_t)23682560) return;  // insufficient workspace -> fail loudly

  const int* esrc = ei;
  const int* edst = ei + E_;

  k_zero   <<<625, 256, 0, stream>>>(cnts, stats);
  k_count  <<<E_ / 256, 256, 0, stream>>>(edst, cnts);
  k_scan1  <<<NSB_, 256, 0, stream>>>(cnts, bsum);
  k_scan2  <<<1, 1, 0, stream>>>(bsum);
  k_scan3  <<<NSB_, 256, 0, stream>>>(cnts, bsum, offs);
  k_scatter<<<E_ / 256, 256, 0, stream>>>(esrc, edst, cnts, srcs);
  k_perm   <<<T_ * B_, 256, 0, stream>>>(W, x, y, stats);
  k_mean   <<<1, 1, 0, stream>>>(stats);
  k_ssq    <<<625, 256, 0, stream>>>(y, stats);
  k_noise  <<<625, 256, 0, stream>>>(y, stats, x0);
  k_gat<<<625, 256, 0, stream>>>(x0, y, offs, srcs, gw, asrc, adst, gbias, bng, bnb, bnm, bnv, x1);
  k_gat<<<625, 256, 0, stream>>>(x1, y, offs, srcs, gw, asrc, adst, gbias, bng, bnb, bnm, bnv, x0);
  k_gat<<<625, 256, 0, stream>>>(x0, y, offs, srcs, gw, asrc, adst, gbias, bng, bnb, bnm, bnv, x1);
  k_gat<<<625, 256, 0, stream>>>(x1, y, offs, srcs, gw, asrc, adst, gbias, bng, bnb, bnm, bnv, x0);
  k_pool<<<B_, 256, 0, stream>>>(x0, dv, lw, lb, out);
}

// Round 2
// 989.786 us; speedup vs baseline: 1.2851x; 1.2851x over previous
//
#include <hip/hip_runtime.h>
#include <stdint.h>
#include <math.h>

#define B_   16
#define T_   50
#define C_   200
#define N_   10000      // T_*C_
#define NT_  160000     // B_*N_
#define H_   8
#define E_   5120000
#define EPS_ 1e-5f
#define NB_  625        // CSR buckets: dst>>8, NT_/256

// ---------------- Threefry-2x32 (JAX) ----------------
struct TF2C { unsigned a, b; };
constexpr unsigned rotl32c(unsigned v, int r){ return (v << r) | (v >> (32 - r)); }
constexpr TF2C tf_const(unsigned k0, unsigned k1, unsigned x0, unsigned x1){
  unsigned ks2 = k0 ^ k1 ^ 0x1BD11BDAu;
  unsigned ks[3] = {k0, k1, ks2};
  x0 += k0; x1 += k1;
  const int RA[4] = {13, 15, 26, 6};
  const int RB[4] = {17, 29, 16, 24};
  for (int g = 0; g < 5; ++g){
    for (int r = 0; r < 4; ++r){
      int rr = (g & 1) ? RB[r] : RA[r];
      x0 += x1; x1 = rotl32c(x1, rr); x1 ^= x0;
    }
    x0 += ks[(g + 1) % 3];
    x1 += ks[(g + 2) % 3] + (unsigned)(g + 1);
  }
  return TF2C{x0, x1};
}
constexpr TF2C KG = tf_const(0u, 42u, 0u, 0u);  // fold_in(key(42),0) -> gumbel key
constexpr TF2C KN = tf_const(0u, 42u, 0u, 1u);  // fold_in(key(42),1) -> noise key

__device__ __forceinline__ unsigned rotl32(unsigned v, int r){ return (v << r) | (v >> (32 - r)); }
__device__ __forceinline__ void tf2(unsigned k0, unsigned k1, unsigned x0, unsigned x1,
                                    unsigned &o0, unsigned &o1){
  unsigned ks2 = k0 ^ k1 ^ 0x1BD11BDAu;
  x0 += k0; x1 += k1;
#define TFR_(R) { x0 += x1; x1 = rotl32(x1, R); x1 ^= x0; }
  TFR_(13) TFR_(15) TFR_(26) TFR_(6)  x0 += k1;  x1 += ks2 + 1u;
  TFR_(17) TFR_(29) TFR_(16) TFR_(24) x0 += ks2; x1 += k0 + 2u;
  TFR_(13) TFR_(15) TFR_(26) TFR_(6)  x0 += k0;  x1 += k1 + 3u;
  TFR_(17) TFR_(29) TFR_(16) TFR_(24) x0 += k1;  x1 += ks2 + 4u;
  TFR_(13) TFR_(15) TFR_(26) TFR_(6)  x0 += ks2; x1 += k0 + 5u;
#undef TFR_
  o0 = x0; o1 = x1;
}
__device__ __forceinline__ unsigned rbits(unsigned ka, unsigned kb, unsigned m){
  unsigned a, b; tf2(ka, kb, 0u, m, a, b); return a ^ b;
}

// XLA ErfInv (f32, Giles)
__device__ __forceinline__ float erfinv_xla(float x){
  float w = -log1pf(-x * x);
  float p;
  if (w < 5.0f){
    w = w - 2.5f;
    p = 2.81022636e-08f;
    p = fmaf(p, w, 3.43273939e-07f);
    p = fmaf(p, w, -3.5233877e-06f);
    p = fmaf(p, w, -4.39150654e-06f);
    p = fmaf(p, w, 0.00021858087f);
    p = fmaf(p, w, -0.00125372503f);
    p = fmaf(p, w, -0.00417768164f);
    p = fmaf(p, w, 0.246640727f);
    p = fmaf(p, w, 1.50140941f);
  } else {
    w = sqrtf(w) - 3.0f;
    p = -0.000200214257f;
    p = fmaf(p, w, 0.000100950558f);
    p = fmaf(p, w, 0.00134934322f);
    p = fmaf(p, w, -0.00367342844f);
    p = fmaf(p, w, 0.00573950773f);
    p = fmaf(p, w, -0.0076224613f);
    p = fmaf(p, w, 0.00943887047f);
    p = fmaf(p, w, 1.00167406f);
    p = fmaf(p, w, 2.83297682f);
  }
  return p * x;
}

// ---------------- bucketed CSR build ----------------
// bcnt/bcur are padded: one counter per 64B line (stride 16 ints) to avoid
// same-line atomic serialization at the L2 atomic units.

__global__ void k_init(int* __restrict__ bcnt, float* __restrict__ stats){
  int i = blockIdx.x * 256 + threadIdx.x;
  if (i < NB_ * 16) bcnt[i] = 0;
  if (i < 8) stats[i] = 0.f;
}

__global__ void k_hist(const int* __restrict__ dst, int* __restrict__ bcnt){
  __shared__ int h[NB_];
  for (int i = threadIdx.x; i < NB_; i += 256) h[i] = 0;
  __syncthreads();
  int stride = gridDim.x * 256;
  for (int e = blockIdx.x * 256 + threadIdx.x; e < E_; e += stride)
    atomicAdd(&h[dst[e] >> 8], 1);
  __syncthreads();
  for (int i = threadIdx.x; i < NB_; i += 256){
    int v = h[i];
    if (v) atomicAdd(&bcnt[i * 16], v);
  }
}

__global__ void k_bscan(const int* __restrict__ bcnt, int* __restrict__ boff,
                        int* __restrict__ bcur){
  __shared__ int ts[256];
  int tid = threadIdx.x;
  int i0 = tid * 3;
  int c0 = (i0 + 0 < NB_) ? bcnt[(i0 + 0) * 16] : 0;
  int c1 = (i0 + 1 < NB_) ? bcnt[(i0 + 1) * 16] : 0;
  int c2 = (i0 + 2 < NB_) ? bcnt[(i0 + 2) * 16] : 0;
  int s = c0 + c1 + c2;
  ts[tid] = s;
  __syncthreads();
  for (int d = 1; d < 256; d <<= 1){
    int t = (tid >= d) ? ts[tid - d] : 0;
    __syncthreads();
    ts[tid] += t;
    __syncthreads();
  }
  int run = ts[tid] - s;
  if (i0 + 0 <= NB_){ boff[i0 + 0] = run; if (i0 + 0 < NB_) bcur[(i0 + 0) * 16] = run; run += c0; }
  if (i0 + 1 <= NB_){ boff[i0 + 1] = run; if (i0 + 1 < NB_) bcur[(i0 + 1) * 16] = run; run += c1; }
  if (i0 + 2 <= NB_){ boff[i0 + 2] = run; if (i0 + 2 < NB_) bcur[(i0 + 2) * 16] = run; run += c2; }
}

__global__ void k_append(const int* __restrict__ src, const int* __restrict__ dst,
                         int* __restrict__ bcur, unsigned* __restrict__ ebuf){
  int e = blockIdx.x * 256 + threadIdx.x;
  if (e >= E_) return;
  int d = dst[e];
  int pos = atomicAdd(&bcur[(d >> 8) * 16], 1);
  ebuf[pos] = ((unsigned)src[e] << 8) | (unsigned)(d & 255);
}

// one workgroup per bucket: exact per-node offsets + in-bucket scatter
__global__ __launch_bounds__(256)
void k_bcsr(const int* __restrict__ boff, const unsigned* __restrict__ ebuf,
            int* __restrict__ offs, int* __restrict__ srcs){
  __shared__ int cnt[256];
  __shared__ int ts[256];
  int b = blockIdx.x, tid = threadIdx.x;
  int e0 = boff[b], e1 = boff[b + 1];
  cnt[tid] = 0;
  __syncthreads();
  for (int e = e0 + tid; e < e1; e += 256)
    atomicAdd(&cnt[ebuf[e] & 255u], 1);
  __syncthreads();
  int v = cnt[tid];
  ts[tid] = v;
  __syncthreads();
  for (int d = 1; d < 256; d <<= 1){
    int t = (tid >= d) ? ts[tid - d] : 0;
    __syncthreads();
    ts[tid] += t;
    __syncthreads();
  }
  int excl = ts[tid] - v;
  offs[b * 256 + tid] = e0 + excl;
  __syncthreads();
  cnt[tid] = excl;              // reuse as in-bucket cursor
  __syncthreads();
  for (int e = e0 + tid; e < e1; e += 256){
    unsigned pk = ebuf[e];
    int pos = e0 + atomicAdd(&cnt[pk & 255u], 1);
    srcs[pos] = (int)(pk >> 8);
  }
  if (b == 0 && tid == 0) offs[NT_] = E_;
}

// ---------------- permutation layer ----------------
#define CHUNK_ 40
#define CHP_   41

__global__ __launch_bounds__(256, 4)
void k_perm(const float* __restrict__ W, const float* __restrict__ x,
            float* __restrict__ y, float* __restrict__ stats){
  __shared__ float xsh[C_];
  __shared__ float zch[C_ * CHP_];
  __shared__ float ypart[4 * C_];
  __shared__ float sred[8];

  const int bid = blockIdx.x;            // t*B_ + b
  const int t = bid / B_;
  const int b = bid - t * B_;
  const unsigned base_m = (unsigned)bid * (unsigned)(C_ * C_);
  const int xoff = (b * T_ + t) * C_;
  const int tid = threadIdx.x;
  const int w = tid >> 6, l = tid & 63;

  if (tid < C_) xsh[tid] = x[xoff + tid];

  float yacc0 = 0.f, yacc1 = 0.f, yacc2 = 0.f, yacc3 = 0.f;

  for (int j0 = 0; j0 < C_; j0 += CHUNK_){
    __syncthreads();
    for (int e = tid; e < C_ * CHUNK_; e += 256){
      int i = e / CHUNK_;
      int jj = e - i * CHUNK_;
      unsigned m = base_m + (unsigned)(i * C_ + j0 + jj);
      unsigned bits = rbits(KG.a, KG.b, m);
      float f = __uint_as_float((bits >> 9) | 0x3f800000u) - 1.0f;   // [0,1)
      float u = fmaxf(1e-10f, f + 1e-10f);                           // uniform(1e-10, 1)
      float g = -logf(-logf(u));
      zch[i * CHP_ + jj] = W[(size_t)base_m + (size_t)(i * C_ + j0 + jj)] + g;
    }
    __syncthreads();
    for (int jj = w; jj < CHUNK_; jj += 4){
      float z0 = zch[l * CHP_ + jj];
      float z1 = zch[(l + 64) * CHP_ + jj];
      float z2 = zch[(l + 128) * CHP_ + jj];
      float z3 = (l < 8) ? zch[(l + 192) * CHP_ + jj] : -INFINITY;
      float mx = fmaxf(fmaxf(z0, z1), fmaxf(z2, z3));
#pragma unroll
      for (int s = 32; s >= 1; s >>= 1) mx = fmaxf(mx, __shfl_xor(mx, s, 64));
      float e0 = expf(z0 - mx), e1 = expf(z1 - mx), e2 = expf(z2 - mx);
      float e3 = (l < 8) ? expf(z3 - mx) : 0.0f;
      float se = e0 + e1 + e2 + e3;
#pragma unroll
      for (int s = 32; s >= 1; s >>= 1) se += __shfl_xor(se, s, 64);
      float wj = xsh[j0 + jj] / se;
      yacc0 = fmaf(e0, wj, yacc0);
      yacc1 = fmaf(e1, wj, yacc1);
      yacc2 = fmaf(e2, wj, yacc2);
      yacc3 = fmaf(e3, wj, yacc3);
    }
  }
  __syncthreads();
  ypart[w * C_ + l] = yacc0;
  ypart[w * C_ + l + 64] = yacc1;
  ypart[w * C_ + l + 128] = yacc2;
  if (l < 8) ypart[w * C_ + l + 192] = yacc3;
  __syncthreads();

  float nzs = 0.f, nzc = 0.f;
  if (tid < C_){
    float v = ypart[tid] + ypart[C_ + tid] + ypart[2 * C_ + tid] + ypart[3 * C_ + tid];
    y[xoff + tid] = v;
    if (v != 0.0f){ nzs = v; nzc = 1.0f; }
  }
#pragma unroll
  for (int s = 32; s >= 1; s >>= 1){
    nzs += __shfl_xor(nzs, s, 64);
    nzc += __shfl_xor(nzc, s, 64);
  }
  if (l == 0){ sred[w] = nzs; sred[4 + w] = nzc; }
  __syncthreads();
  if (tid == 0){
    atomicAdd(&stats[0], sred[0] + sred[1] + sred[2] + sred[3]);
    atomicAdd(&stats[1], sred[4] + sred[5] + sred[6] + sred[7]);
  }
}

// ---------------- noise stats ----------------
__global__ void k_mean(float* __restrict__ stats){ stats[2] = stats[0] / stats[1]; }

__global__ void k_ssq(const float* __restrict__ y, float* __restrict__ stats){
  __shared__ float sred[4];
  int n = blockIdx.x * 256 + threadIdx.x;
  float mean = stats[2];
  float a = 0.f;
  float v = y[n];
  if (v != 0.f){ float d = v - mean; a = d * d; }
#pragma unroll
  for (int s = 32; s >= 1; s >>= 1) a += __shfl_xor(a, s, 64);
  int w = threadIdx.x >> 6, l = threadIdx.x & 63;
  if (l == 0) sred[w] = a;
  __syncthreads();
  if (threadIdx.x == 0) atomicAdd(&stats[3], sred[0] + sred[1] + sred[2] + sred[3]);
}

__global__ void k_noise(const float* __restrict__ y, const float* __restrict__ stats,
                        float* __restrict__ x0){
  int n = blockIdx.x * 256 + threadIdx.x;
  float v = y[n];
  if (v != 0.0f){ x0[n] = v; return; }
  float std_ = sqrtf(stats[3] / (stats[1] - 1.0f));
  float scale = std_ / 100.0f;
  unsigned bits = rbits(KN.a, KN.b, (unsigned)n);
  float f = __uint_as_float((bits >> 9) | 0x3f800000u) - 1.0f;
  float u = f * 2.0f + (-0.99999994f);
  u = fmaxf(-0.99999994f, u);
  float nrm = 1.41421356237f * erfinv_xla(u);
  x0[n] = scale * nrm;
}

// ---------------- fused GAT pass (+BN+SiLU+residual) ----------------
__global__ __launch_bounds__(256)
void k_gat(const float* __restrict__ xin, const float* __restrict__ xres,
           const int* __restrict__ offs, const int* __restrict__ srcs,
           const float* __restrict__ gw, const float* __restrict__ asrc,
           const float* __restrict__ adst, const float* __restrict__ gbias,
           const float* __restrict__ bng, const float* __restrict__ bnb,
           const float* __restrict__ bnm, const float* __restrict__ bnv,
           float* __restrict__ xout){
  int n = blockIdx.x * 256 + threadIdx.x;
  if (n >= NT_) return;
  float wv[H_], cs[H_], cd[H_];
#pragma unroll
  for (int h = 0; h < H_; ++h){
    wv[h] = gw[h];
    cs[h] = wv[h] * asrc[h];
    cd[h] = wv[h] * adst[h];
  }
  float xn = xin[n];
  int e0 = offs[n], e1 = offs[n + 1];

  float mh[H_];
#pragma unroll
  for (int h = 0; h < H_; ++h){
    float v = cs[h] * xn + cd[h] * xn;        // self loop
    mh[h] = (v > 0.f) ? v : 0.2f * v;
  }
  for (int e = e0; e < e1; ++e){
    float xs = xin[srcs[e]];
#pragma unroll
    for (int h = 0; h < H_; ++h){
      float v = cs[h] * xs + cd[h] * xn;
      v = (v > 0.f) ? v : 0.2f * v;
      mh[h] = fmaxf(mh[h], v);
    }
  }
  float den[H_], num[H_];
#pragma unroll
  for (int h = 0; h < H_; ++h){
    float v = cs[h] * xn + cd[h] * xn;
    v = (v > 0.f) ? v : 0.2f * v;
    float ee = expf(v - mh[h]);
    den[h] = ee; num[h] = ee * xn;
  }
  for (int e = e0; e < e1; ++e){
    float xs = xin[srcs[e]];
#pragma unroll
    for (int h = 0; h < H_; ++h){
      float v = cs[h] * xs + cd[h] * xn;
      v = (v > 0.f) ? v : 0.2f * v;
      float ee = expf(v - mh[h]);
      den[h] += ee; num[h] += ee * xs;
    }
  }
  float o = 0.f;
#pragma unroll
  for (int h = 0; h < H_; ++h) o += wv[h] * num[h] / den[h];
  o = o * 0.125f + gbias[0];
  o = (o - bnm[0]) / sqrtf(bnv[0] + EPS_) * bng[0] + bnb[0];
  o = o / (1.0f + expf(-o));                  // silu
  xout[n] = o + xres[n];
}

// ---------------- final pool + linear + relu ----------------
__global__ void k_pool(const float* __restrict__ xf, const float* __restrict__ dv,
                       const float* __restrict__ lw, const float* __restrict__ lb,
                       float* __restrict__ out){
  __shared__ float sred[4];
  int b = blockIdx.x, tid = threadIdx.x;
  float m = -INFINITY;
  for (int li = tid; li < N_; li += 256){
    float v = xf[b * N_ + li] * dv[li];
    m = fmaxf(m, v);
  }
#pragma unroll
  for (int s = 32; s >= 1; s >>= 1) m = fmaxf(m, __shfl_xor(m, s, 64));
  int w = tid >> 6, l = tid & 63;
  if (l == 0) sred[w] = m;
  __syncthreads();
  if (tid == 0){
    float p = fmaxf(fmaxf(sred[0], sred[1]), fmaxf(sred[2], sred[3]));
    float o = p * lw[0] + lb[0];
    out[b] = (o > 0.f) ? o : 0.f;
  }
}

// ---------------- launch ----------------
extern "C" void kernel_launch(void* const* d_in, const int* in_sizes, int n_in,
                              void* d_out, int out_size, void* d_ws, size_t ws_size,
                              hipStream_t stream){
  const float* x     = (const float*)d_in[0];
  const int*   ei    = (const int*)d_in[1];
  const float* W     = (const float*)d_in[3];
  const float* dv    = (const float*)d_in[4];
  const float* gw    = (const float*)d_in[5];
  const float* asrc  = (const float*)d_in[6];
  const float* adst  = (const float*)d_in[7];
  const float* gbias = (const float*)d_in[8];
  const float* bng   = (const float*)d_in[9];
  const float* bnb   = (const float*)d_in[10];
  const float* bnm   = (const float*)d_in[11];
  const float* bnv   = (const float*)d_in[12];
  const float* lw    = (const float*)d_in[13];
  const float* lb    = (const float*)d_in[14];
  float* out = (float*)d_out;

  char* ws = (char*)d_ws;
  int*      offs  = (int*)     (ws + 0);          // NT_+1 ints
  int*      srcs  = (int*)     (ws + 640256);     // E_ ints
  unsigned* ebuf  = (unsigned*)(ws + 21120256);   // E_ u32 (packed src<<8|dstlocal)
  float*    y     = (float*)   (ws + 41600256);   // NT_ f32 (x_res)
  float*    x0    = (float*)   (ws + 42240256);   // NT_ f32
  float*    x1    = (float*)   (ws + 42880256);   // NT_ f32
  int*      bcnt  = (int*)     (ws + 43520256);   // NB_*16 ints (line-padded)
  int*      boff  = (int*)     (ws + 43560256);   // NB_+1 ints
  int*      bcur  = (int*)     (ws + 43562768);   // NB_*16 ints (line-padded)
  float*    stats = (float*)   (ws + 43602768);   // 8 f32
  if (ws_size < (size_t)43602800) return;         // insufficient workspace -> fail loudly

  const int* esrc = ei;
  const int* edst = ei + E_;

  k_init  <<<40, 256, 0, stream>>>(bcnt, stats);
  k_hist  <<<512, 256, 0, stream>>>(edst, bcnt);
  k_bscan <<<1, 256, 0, stream>>>(bcnt, boff, bcur);
  k_append<<<E_ / 256, 256, 0, stream>>>(esrc, edst, bcur, ebuf);
  k_bcsr  <<<NB_, 256, 0, stream>>>(boff, ebuf, offs, srcs);
  k_perm  <<<T_ * B_, 256, 0, stream>>>(W, x, y, stats);
  k_mean  <<<1, 1, 0, stream>>>(stats);
  k_ssq   <<<625, 256, 0, stream>>>(y, stats);
  k_noise <<<625, 256, 0, stream>>>(y, stats, x0);
  k_gat<<<625, 256, 0, stream>>>(x0, y, offs, srcs, gw, asrc, adst, gbias, bng, bnb, bnm, bnv, x1);
  k_gat<<<625, 256, 0, stream>>>(x1, y, offs, srcs, gw, asrc, adst, gbias, bng, bnb, bnm, bnv, x0);
  k_gat<<<625, 256, 0, stream>>>(x0, y, offs, srcs, gw, asrc, adst, gbias, bng, bnb, bnm, bnv, x1);
  k_gat<<<625, 256, 0, stream>>>(x1, y, offs, srcs, gw, asrc, adst, gbias, bng, bnb, bnm, bnv, x0);
  k_pool<<<B_, 256, 0, stream>>>(x0, dv, lw, lb, out);
}

// Round 3
// 491.330 us; speedup vs baseline: 2.5889x; 2.0145x over previous
//
#include <hip/hip_runtime.h>
#include <stdint.h>
#include <math.h>

#define B_   16
#define T_   50
#define C_   200
#define N_   10000      // T_*C_
#define NT_  160000     // B_*N_
#define H_   8
#define E_   5120000
#define EPS_ 1e-5f
#define NB_  625        // CSR buckets: dst>>8
#define EB_  256        // edge blocks for hist/append
#define EPB_ 20000      // edges per block (E_/EB_)
#define GB_  40         // chunks per graph (gat/pool)
#define GC_  250        // nodes per chunk (N_/GB_)

// ---------------- Threefry-2x32 (JAX) ----------------
struct TF2C { unsigned a, b; };
constexpr unsigned rotl32c(unsigned v, int r){ return (v << r) | (v >> (32 - r)); }
constexpr TF2C tf_const(unsigned k0, unsigned k1, unsigned x0, unsigned x1){
  unsigned ks2 = k0 ^ k1 ^ 0x1BD11BDAu;
  unsigned ks[3] = {k0, k1, ks2};
  x0 += k0; x1 += k1;
  const int RA[4] = {13, 15, 26, 6};
  const int RB[4] = {17, 29, 16, 24};
  for (int g = 0; g < 5; ++g){
    for (int r = 0; r < 4; ++r){
      int rr = (g & 1) ? RB[r] : RA[r];
      x0 += x1; x1 = rotl32c(x1, rr); x1 ^= x0;
    }
    x0 += ks[(g + 1) % 3];
    x1 += ks[(g + 2) % 3] + (unsigned)(g + 1);
  }
  return TF2C{x0, x1};
}
constexpr TF2C KG = tf_const(0u, 42u, 0u, 0u);
constexpr TF2C KN = tf_const(0u, 42u, 0u, 1u);

__device__ __forceinline__ unsigned rotl32(unsigned v, int r){ return (v << r) | (v >> (32 - r)); }
__device__ __forceinline__ void tf2(unsigned k0, unsigned k1, unsigned x0, unsigned x1,
                                    unsigned &o0, unsigned &o1){
  unsigned ks2 = k0 ^ k1 ^ 0x1BD11BDAu;
  x0 += k0; x1 += k1;
#define TFR_(R) { x0 += x1; x1 = rotl32(x1, R); x1 ^= x0; }
  TFR_(13) TFR_(15) TFR_(26) TFR_(6)  x0 += k1;  x1 += ks2 + 1u;
  TFR_(17) TFR_(29) TFR_(16) TFR_(24) x0 += ks2; x1 += k0 + 2u;
  TFR_(13) TFR_(15) TFR_(26) TFR_(6)  x0 += k0;  x1 += k1 + 3u;
  TFR_(17) TFR_(29) TFR_(16) TFR_(24) x0 += k1;  x1 += ks2 + 4u;
  TFR_(13) TFR_(15) TFR_(26) TFR_(6)  x0 += ks2; x1 += k0 + 5u;
#undef TFR_
  o0 = x0; o1 = x1;
}
__device__ __forceinline__ unsigned rbits(unsigned ka, unsigned kb, unsigned m){
  unsigned a, b; tf2(ka, kb, 0u, m, a, b); return a ^ b;
}

__device__ __forceinline__ float erfinv_xla(float x){
  float w = -log1pf(-x * x);
  float p;
  if (w < 5.0f){
    w = w - 2.5f;
    p = 2.81022636e-08f;
    p = fmaf(p, w, 3.43273939e-07f);
    p = fmaf(p, w, -3.5233877e-06f);
    p = fmaf(p, w, -4.39150654e-06f);
    p = fmaf(p, w, 0.00021858087f);
    p = fmaf(p, w, -0.00125372503f);
    p = fmaf(p, w, -0.00417768164f);
    p = fmaf(p, w, 0.246640727f);
    p = fmaf(p, w, 1.50140941f);
  } else {
    w = sqrtf(w) - 3.0f;
    p = -0.000200214257f;
    p = fmaf(p, w, 0.000100950558f);
    p = fmaf(p, w, 0.00134934322f);
    p = fmaf(p, w, -0.00367342844f);
    p = fmaf(p, w, 0.00573950773f);
    p = fmaf(p, w, -0.0076224613f);
    p = fmaf(p, w, 0.00943887047f);
    p = fmaf(p, w, 1.00167406f);
    p = fmaf(p, w, 2.83297682f);
  }
  return p * x;
}

// ---------------- CSR build: atomic-free placement ----------------
__global__ void k_init(float* __restrict__ stats){
  if (threadIdx.x < 8) stats[threadIdx.x] = 0.f;
}

// per-(block,bucket) histogram; cnt[blk*NB_+b]
__global__ __launch_bounds__(256)
void k_hist(const int* __restrict__ dst, int* __restrict__ cnt){
  __shared__ int h[NB_];
  int tid = threadIdx.x, blk = blockIdx.x;
  for (int i = tid; i < NB_; i += 256) h[i] = 0;
  __syncthreads();
  int e0 = blk * EPB_;
  for (int i = tid; i < EPB_; i += 256)
    atomicAdd(&h[dst[e0 + i] >> 8], 1);
  __syncthreads();
  for (int i = tid; i < NB_; i += 256) cnt[blk * NB_ + i] = h[i];
}

// bucket totals: bsum[b] = sum over blk of cnt[blk][b]
__global__ __launch_bounds__(256)
void k_sumb(const int* __restrict__ cnt, int* __restrict__ bsum){
  __shared__ int sred[4];
  int b = blockIdx.x, tid = threadIdx.x;
  int v = cnt[tid * NB_ + b];            // EB_ == 256 == blockDim
#pragma unroll
  for (int s = 32; s >= 1; s >>= 1) v += __shfl_xor(v, s, 64);
  int w = tid >> 6, l = tid & 63;
  if (l == 0) sred[w] = v;
  __syncthreads();
  if (tid == 0) bsum[b] = sred[0] + sred[1] + sred[2] + sred[3];
}

// exclusive scan of 625 bucket totals -> boff
__global__ void k_scanb(const int* __restrict__ bsum, int* __restrict__ boff){
  __shared__ int ts[256];
  int tid = threadIdx.x;
  int i0 = tid * 3;
  int c0 = (i0 + 0 < NB_) ? bsum[i0 + 0] : 0;
  int c1 = (i0 + 1 < NB_) ? bsum[i0 + 1] : 0;
  int c2 = (i0 + 2 < NB_) ? bsum[i0 + 2] : 0;
  int s = c0 + c1 + c2;
  ts[tid] = s;
  __syncthreads();
  for (int d = 1; d < 256; d <<= 1){
    int t = (tid >= d) ? ts[tid - d] : 0;
    __syncthreads();
    ts[tid] += t;
    __syncthreads();
  }
  int run = ts[tid] - s;
  if (i0 + 0 <= NB_){ boff[i0 + 0] = run; run += c0; }
  if (i0 + 1 <= NB_){ boff[i0 + 1] = run; run += c1; }
  if (i0 + 2 <= NB_){ boff[i0 + 2] = run; run += c2; }
}

// per-bucket exclusive scan over blocks -> gscan[blk*NB_+b] = region base
__global__ __launch_bounds__(256)
void k_scanc(const int* __restrict__ cnt, const int* __restrict__ boff,
             int* __restrict__ gscan){
  __shared__ int ts[256];
  int b = blockIdx.x, tid = threadIdx.x;
  int v = cnt[tid * NB_ + b];
  ts[tid] = v;
  __syncthreads();
  for (int d = 1; d < 256; d <<= 1){
    int t = (tid >= d) ? ts[tid - d] : 0;
    __syncthreads();
    ts[tid] += t;
    __syncthreads();
  }
  gscan[tid * NB_ + b] = boff[b] + ts[tid] - v;
}

// atomic-free append: each block writes only its own sub-regions
__global__ __launch_bounds__(256)
void k_append(const int* __restrict__ src, const int* __restrict__ dst,
              const int* __restrict__ gscan, unsigned* __restrict__ ebuf){
  __shared__ int gb[NB_];
  __shared__ int lc[NB_];
  int tid = threadIdx.x, blk = blockIdx.x;
  for (int i = tid; i < NB_; i += 256){ gb[i] = gscan[blk * NB_ + i]; lc[i] = 0; }
  __syncthreads();
  int e0 = blk * EPB_;
  for (int i = tid; i < EPB_; i += 256){
    int e = e0 + i;
    int d = dst[e];
    int b = d >> 8;
    int r = atomicAdd(&lc[b], 1);
    ebuf[gb[b] + r] = ((unsigned)src[e] << 8) | (unsigned)(d & 255);
  }
}

// one workgroup per bucket: exact per-node offsets + in-bucket scatter
__global__ __launch_bounds__(256)
void k_bcsr(const int* __restrict__ boff, const unsigned* __restrict__ ebuf,
            int* __restrict__ offs, int* __restrict__ srcs){
  __shared__ int cnt[256];
  __shared__ int ts[256];
  int b = blockIdx.x, tid = threadIdx.x;
  int e0 = boff[b], e1 = boff[b + 1];
  cnt[tid] = 0;
  __syncthreads();
  for (int e = e0 + tid; e < e1; e += 256)
    atomicAdd(&cnt[ebuf[e] & 255u], 1);
  __syncthreads();
  int v = cnt[tid];
  ts[tid] = v;
  __syncthreads();
  for (int d = 1; d < 256; d <<= 1){
    int t = (tid >= d) ? ts[tid - d] : 0;
    __syncthreads();
    ts[tid] += t;
    __syncthreads();
  }
  int excl = ts[tid] - v;
  offs[b * 256 + tid] = e0 + excl;
  __syncthreads();
  cnt[tid] = excl;
  __syncthreads();
  for (int e = e0 + tid; e < e1; e += 256){
    unsigned pk = ebuf[e];
    int pos = e0 + atomicAdd(&cnt[pk & 255u], 1);
    srcs[pos] = (int)(pk >> 8);
  }
  if (b == 0 && tid == 0) offs[NT_] = E_;
}

// ---------------- permutation layer ----------------
#define CHUNK_ 40
#define CHP_   41

__global__ __launch_bounds__(256, 4)
void k_perm(const float* __restrict__ W, const float* __restrict__ x,
            float* __restrict__ y, float* __restrict__ stats){
  __shared__ float xsh[C_];
  __shared__ float zch[C_ * CHP_];
  __shared__ float ypart[4 * C_];
  __shared__ float sred[8];

  const int bid = blockIdx.x;
  const int t = bid / B_;
  const int b = bid - t * B_;
  const unsigned base_m = (unsigned)bid * (unsigned)(C_ * C_);
  const int xoff = (b * T_ + t) * C_;
  const int tid = threadIdx.x;
  const int w = tid >> 6, l = tid & 63;

  if (tid < C_) xsh[tid] = x[xoff + tid];

  float yacc0 = 0.f, yacc1 = 0.f, yacc2 = 0.f, yacc3 = 0.f;

  for (int j0 = 0; j0 < C_; j0 += CHUNK_){
    __syncthreads();
    for (int e = tid; e < C_ * CHUNK_; e += 256){
      int i = e / CHUNK_;
      int jj = e - i * CHUNK_;
      unsigned m = base_m + (unsigned)(i * C_ + j0 + jj);
      unsigned bits = rbits(KG.a, KG.b, m);
      float f = __uint_as_float((bits >> 9) | 0x3f800000u) - 1.0f;
      float u = fmaxf(1e-10f, f + 1e-10f);
      float g = -logf(-logf(u));
      zch[i * CHP_ + jj] = W[(size_t)base_m + (size_t)(i * C_ + j0 + jj)] + g;
    }
    __syncthreads();
    for (int jj = w; jj < CHUNK_; jj += 4){
      float z0 = zch[l * CHP_ + jj];
      float z1 = zch[(l + 64) * CHP_ + jj];
      float z2 = zch[(l + 128) * CHP_ + jj];
      float z3 = (l < 8) ? zch[(l + 192) * CHP_ + jj] : -INFINITY;
      float mx = fmaxf(fmaxf(z0, z1), fmaxf(z2, z3));
#pragma unroll
      for (int s = 32; s >= 1; s >>= 1) mx = fmaxf(mx, __shfl_xor(mx, s, 64));
      float e0 = expf(z0 - mx), e1 = expf(z1 - mx), e2 = expf(z2 - mx);
      float e3 = (l < 8) ? expf(z3 - mx) : 0.0f;
      float se = e0 + e1 + e2 + e3;
#pragma unroll
      for (int s = 32; s >= 1; s >>= 1) se += __shfl_xor(se, s, 64);
      float wj = xsh[j0 + jj] / se;
      yacc0 = fmaf(e0, wj, yacc0);
      yacc1 = fmaf(e1, wj, yacc1);
      yacc2 = fmaf(e2, wj, yacc2);
      yacc3 = fmaf(e3, wj, yacc3);
    }
  }
  __syncthreads();
  ypart[w * C_ + l] = yacc0;
  ypart[w * C_ + l + 64] = yacc1;
  ypart[w * C_ + l + 128] = yacc2;
  if (l < 8) ypart[w * C_ + l + 192] = yacc3;
  __syncthreads();

  float nzs = 0.f, nzc = 0.f;
  if (tid < C_){
    float v = ypart[tid] + ypart[C_ + tid] + ypart[2 * C_ + tid] + ypart[3 * C_ + tid];
    y[xoff + tid] = v;
    if (v != 0.0f){ nzs = v; nzc = 1.0f; }
  }
#pragma unroll
  for (int s = 32; s >= 1; s >>= 1){
    nzs += __shfl_xor(nzs, s, 64);
    nzc += __shfl_xor(nzc, s, 64);
  }
  if (l == 0){ sred[w] = nzs; sred[4 + w] = nzc; }
  __syncthreads();
  if (tid == 0){
    atomicAdd(&stats[0], sred[0] + sred[1] + sred[2] + sred[3]);
    atomicAdd(&stats[1], sred[4] + sred[5] + sred[6] + sred[7]);
  }
}

// ---------------- noise stats ----------------
__global__ void k_mean(float* __restrict__ stats){ stats[2] = stats[0] / stats[1]; }

__global__ void k_ssq(const float* __restrict__ y, float* __restrict__ stats){
  __shared__ float sred[4];
  int n = blockIdx.x * 256 + threadIdx.x;
  float mean = stats[2];
  float a = 0.f;
  float v = y[n];
  if (v != 0.f){ float d = v - mean; a = d * d; }
#pragma unroll
  for (int s = 32; s >= 1; s >>= 1) a += __shfl_xor(a, s, 64);
  int w = threadIdx.x >> 6, l = threadIdx.x & 63;
  if (l == 0) sred[w] = a;
  __syncthreads();
  if (threadIdx.x == 0) atomicAdd(&stats[3], sred[0] + sred[1] + sred[2] + sred[3]);
}

__global__ void k_noise(const float* __restrict__ y, const float* __restrict__ stats,
                        float* __restrict__ x0){
  int n = blockIdx.x * 256 + threadIdx.x;
  float v = y[n];
  if (v != 0.0f){ x0[n] = v; return; }
  float std_ = sqrtf(stats[3] / (stats[1] - 1.0f));
  float scale = std_ / 100.0f;
  unsigned bits = rbits(KN.a, KN.b, (unsigned)n);
  float f = __uint_as_float((bits >> 9) | 0x3f800000u) - 1.0f;
  float u = f * 2.0f + (-0.99999994f);
  u = fmaxf(-0.99999994f, u);
  float nrm = 1.41421356237f * erfinv_xla(u);
  x0[n] = scale * nrm;
}

// ---------------- fused GAT pass: LDS-staged x + online softmax ----------------
__global__ __launch_bounds__(256)
void k_gat(const float* __restrict__ xin, const float* __restrict__ xres,
           const int* __restrict__ offs, const int* __restrict__ srcs,
           const float* __restrict__ gw, const float* __restrict__ asrc,
           const float* __restrict__ adst, const float* __restrict__ gbias,
           const float* __restrict__ bng, const float* __restrict__ bnb,
           const float* __restrict__ bnm, const float* __restrict__ bnv,
           float* __restrict__ xout){
  __shared__ float xsh[N_];                      // whole graph: 40 KB
  int g = blockIdx.x / GB_, c = blockIdx.x - g * GB_;
  int tid = threadIdx.x;
  const float4* xv = (const float4*)(xin + g * N_);
  for (int i = tid; i < N_ / 4; i += 256) ((float4*)xsh)[i] = xv[i];
  __syncthreads();
  if (tid >= GC_) return;

  int nl = c * GC_ + tid;
  int n = g * N_ + nl;
  float xn = xsh[nl];

  float cs[H_], cdxn[H_], wv[H_];
#pragma unroll
  for (int h = 0; h < H_; ++h){
    wv[h] = gw[h];
    cs[h] = wv[h] * asrc[h];
    cdxn[h] = wv[h] * adst[h] * xn;
  }
  // self loop initializes state
  float mh[H_], den[H_], num[H_];
#pragma unroll
  for (int h = 0; h < H_; ++h){
    float v = cs[h] * xn + cdxn[h];
    v = (v > 0.f) ? v : 0.2f * v;
    mh[h] = v; den[h] = 1.f; num[h] = xn;
  }
  int e0 = offs[n], e1 = offs[n + 1];
  for (int e = e0; e < e1; ++e){
    float xs = xsh[srcs[e] - g * N_];
#pragma unroll
    for (int h = 0; h < H_; ++h){
      float v = fmaf(cs[h], xs, cdxn[h]);
      v = (v > 0.f) ? v : 0.2f * v;
      float nm = fmaxf(mh[h], v);
      float corr = __expf(mh[h] - nm);
      float p = __expf(v - nm);
      den[h] = fmaf(den[h], corr, p);
      num[h] = fmaf(num[h], corr, p * xs);
      mh[h] = nm;
    }
  }
  float o = 0.f;
#pragma unroll
  for (int h = 0; h < H_; ++h) o += wv[h] * num[h] / den[h];
  o = o * 0.125f + gbias[0];
  o = (o - bnm[0]) / sqrtf(bnv[0] + EPS_) * bng[0] + bnb[0];
  o = o / (1.0f + __expf(-o));
  xout[n] = o + xres[n];
}

// ---------------- final pool + linear + relu ----------------
__global__ __launch_bounds__(256)
void k_pool1(const float* __restrict__ xf, const float* __restrict__ dv,
             float* __restrict__ pmax){
  __shared__ float sred[4];
  int g = blockIdx.x / GB_, c = blockIdx.x - g * GB_;
  int tid = threadIdx.x;
  float m = -INFINITY;
  if (tid < GC_){
    int nl = c * GC_ + tid;
    m = xf[g * N_ + nl] * dv[nl];
  }
#pragma unroll
  for (int s = 32; s >= 1; s >>= 1) m = fmaxf(m, __shfl_xor(m, s, 64));
  int w = tid >> 6, l = tid & 63;
  if (l == 0) sred[w] = m;
  __syncthreads();
  if (tid == 0)
    pmax[blockIdx.x] = fmaxf(fmaxf(sred[0], sred[1]), fmaxf(sred[2], sred[3]));
}

__global__ void k_pool2(const float* __restrict__ pmax, const float* __restrict__ lw,
                        const float* __restrict__ lb, float* __restrict__ out){
  int b = blockIdx.x, l = threadIdx.x;
  float m = (l < GB_) ? pmax[b * GB_ + l] : -INFINITY;
#pragma unroll
  for (int s = 32; s >= 1; s >>= 1) m = fmaxf(m, __shfl_xor(m, s, 64));
  if (l == 0){
    float o = m * lw[0] + lb[0];
    out[b] = (o > 0.f) ? o : 0.f;
  }
}

// ---------------- launch ----------------
extern "C" void kernel_launch(void* const* d_in, const int* in_sizes, int n_in,
                              void* d_out, int out_size, void* d_ws, size_t ws_size,
                              hipStream_t stream){
  const float* x     = (const float*)d_in[0];
  const int*   ei    = (const int*)d_in[1];
  const float* W     = (const float*)d_in[3];
  const float* dv    = (const float*)d_in[4];
  const float* gw    = (const float*)d_in[5];
  const float* asrc  = (const float*)d_in[6];
  const float* adst  = (const float*)d_in[7];
  const float* gbias = (const float*)d_in[8];
  const float* bng   = (const float*)d_in[9];
  const float* bnb   = (const float*)d_in[10];
  const float* bnm   = (const float*)d_in[11];
  const float* bnv   = (const float*)d_in[12];
  const float* lw    = (const float*)d_in[13];
  const float* lb    = (const float*)d_in[14];
  float* out = (float*)d_out;

  char* ws = (char*)d_ws;
  int*      offs  = (int*)     (ws + 0);          // NT_+1 ints
  int*      srcs  = (int*)     (ws + 640256);     // E_ ints
  // cnt/gscan alias srcs' space (dead until k_bcsr writes srcs)
  int*      cnt   = (int*)     (ws + 640256);     // EB_*NB_ ints (640 KB)
  int*      gscan = (int*)     (ws + 1280256);    // EB_*NB_ ints (640 KB)
  unsigned* ebuf  = (unsigned*)(ws + 21120256);   // E_ u32
  float*    y     = (float*)   (ws + 41600256);   // NT_ f32 (x_res)
  float*    x0    = (float*)   (ws + 42240256);   // NT_ f32
  float*    x1    = (float*)   (ws + 42880256);   // NT_ f32
  int*      bsum  = (int*)     (ws + 43520256);   // NB_ ints
  int*      boff  = (int*)     (ws + 43522816);   // NB_+1 ints
  float*    pmax  = (float*)   (ws + 43525376);   // B_*GB_ f32
  float*    stats = (float*)   (ws + 43527936);   // 8 f32
  if (ws_size < (size_t)43528000) return;

  const int* esrc = ei;
  const int* edst = ei + E_;

  k_init  <<<1, 64, 0, stream>>>(stats);
  k_hist  <<<EB_, 256, 0, stream>>>(edst, cnt);
  k_sumb  <<<NB_, 256, 0, stream>>>(cnt, bsum);
  k_scanb <<<1, 256, 0, stream>>>(bsum, boff);
  k_scanc <<<NB_, 256, 0, stream>>>(cnt, boff, gscan);
  k_append<<<EB_, 256, 0, stream>>>(esrc, edst, gscan, ebuf);
  k_bcsr  <<<NB_, 256, 0, stream>>>(boff, ebuf, offs, srcs);
  k_perm  <<<T_ * B_, 256, 0, stream>>>(W, x, y, stats);
  k_mean  <<<1, 1, 0, stream>>>(stats);
  k_ssq   <<<625, 256, 0, stream>>>(y, stats);
  k_noise <<<625, 256, 0, stream>>>(y, stats, x0);
  k_gat<<<B_ * GB_, 256, 0, stream>>>(x0, y, offs, srcs, gw, asrc, adst, gbias, bng, bnb, bnm, bnv, x1);
  k_gat<<<B_ * GB_, 256, 0, stream>>>(x1, y, offs, srcs, gw, asrc, adst, gbias, bng, bnb, bnm, bnv, x0);
  k_gat<<<B_ * GB_, 256, 0, stream>>>(x0, y, offs, srcs, gw, asrc, adst, gbias, bng, bnb, bnm, bnv, x1);
  k_gat<<<B_ * GB_, 256, 0, stream>>>(x1, y, offs, srcs, gw, asrc, adst, gbias, bng, bnb, bnm, bnv, x0);
  k_pool1 <<<B_ * GB_, 256, 0, stream>>>(x0, dv, pmax);
  k_pool2 <<<B_, 64, 0, stream>>>(pmax, lw, lb, out);
}